// Round 3
// baseline (360.662 us; speedup 1.0000x reference)
//
#include <hip/hip_runtime.h>

// Problem constants
#define D 32
#define K 8
#define NPAIR 36
#define PROWS 576              // packed (4-padded triangular) floats per matrix

// ws layout (float offsets)
#define PMOFF 0                // packed invLc, 8 x 576
#define WOFF 4608              // w_k = invLc_k mu_k, 8 x 32
#define C2OFF 4864             // (c'_t - cmax) * log2(e), 36
#define CMAXOFF 4900
#define TICKOFF 4904           // last-block ticket (unsigned), zeroed by setup2
#define LCOFF 4928             // Lc (cholesky factors), 8 x 32 x 32, upper zeroed
#define PARTOFF 13120          // per-block partial sums (<=1024)

typedef float v2f __attribute__((ext_vector_type(2)));

__host__ __device__ constexpr int gidx(int i, int j) {  // i<=j packed pair index
    return i * 8 + j - i * (i + 1) / 2;
}
__host__ __device__ constexpr int proff(int r) {        // packed row offset
    return 4 * (r / 4 + 1) * (2 * (r / 4) + (r % 4));
}

// ---------------------------------------------------------------------------
// setup1 (R0 verbatim, 8 parallel blocks -- one CU per cluster): spill-free,
// invLc column solve keeps state in LDS. 8 CUs in parallel beats the fused
// single-block version (R1: 53.7us serial).
// ---------------------------------------------------------------------------
__global__ __launch_bounds__(64) void setup1_kernel(
    const float* __restrict__ mu, const float* __restrict__ L,
    float* __restrict__ ws)
{
    __shared__ float sA[D][D + 1];
    __shared__ float sLc[D][D + 1];
    __shared__ float sI[D][D + 1];
    const int k = blockIdx.x;
    const int tid = threadIdx.x;
    const int i = tid & 31;

    for (int e = tid; e < D * D; e += 64) sI[e >> 5][e & 31] = L[k * D * D + e];
    __syncthreads();

    for (int e = tid; e < D * D; e += 64) {
        const int a = e >> 5, c = e & 31;
        float s = (a == c) ? 1.0f : 0.0f;
        #pragma unroll
        for (int b = 0; b < D; ++b) s = fmaf(sI[a][b], sI[c][b], s);
        sA[a][c] = s;
    }
    __syncthreads();

    float lrow[D];
    #pragma unroll
    for (int j = 0; j < D; ++j) {
        if (i == j) {
            float s = sA[j][j];
            #pragma unroll
            for (int b = 0; b < j; ++b) s = fmaf(-lrow[b], lrow[b], s);
            const float d = sqrtf(s);
            lrow[j] = d;
            #pragma unroll
            for (int b = 0; b < j; ++b) sLc[j][b] = lrow[b];
            sLc[j][j] = d;
        }
        __syncthreads();
        if (i > j) {
            float s = sA[i][j];
            #pragma unroll
            for (int b = 0; b < j; ++b) s = fmaf(-lrow[b], sLc[j][b], s);
            lrow[j] = s / sLc[j][j];
        }
    }
    __syncthreads();

    for (int e = tid; e < D * D; e += 64) {
        const int r = e >> 5, c = e & 31;
        ws[LCOFF + k * D * D + e] = (c <= r) ? sLc[r][c] : 0.0f;
    }

    {
        const int j = i;
        #pragma unroll
        for (int ii = 0; ii < D; ++ii) {
            float s = (ii == j) ? 1.0f : 0.0f;
            #pragma unroll
            for (int b = 0; b < ii; ++b) s = fmaf(-sLc[ii][b], sI[b][j], s);
            const float cii = s / sLc[ii][ii];
            sI[ii][j] = cii;
            const int w4 = 4 * (ii / 4 + 1);
            if (j < w4) ws[PMOFF + k * PROWS + proff(ii) + j] = cii;
        }
    }
    __syncthreads();

    {
        float s = 0.0f;
        #pragma unroll
        for (int b = 0; b < D; ++b) s = fmaf(sI[i][b], mu[k * D + b], s);
        ws[WOFF + k * D + i] = s;
    }
}

// ---------------------------------------------------------------------------
// setup2 (R0 verbatim + ticket zero): 256-thread block, all inputs staged to
// LDS before the 36-thread solve.
// ---------------------------------------------------------------------------
#define SLC(kk, r, c) sLc2[(kk) * 1024 + (r) * 32 + (c)]

__global__ __launch_bounds__(256) void setup2_kernel(
    const float* __restrict__ mu, const float* __restrict__ weights,
    float* __restrict__ ws)
{
    __shared__ float sLc2[K * D * D];   // 32 KB
    __shared__ float sMu[K * D];
    __shared__ float sWt[K];
    __shared__ float sLogw[K];
    __shared__ float sCp[NPAIR];
    __shared__ float sCmax;
    const int tid = threadIdx.x;

    {   // stage everything: 8 float4/thread for Lc, 1 float/thread for mu
        const float4* src = (const float4*)(ws + LCOFF);
        float4* dst = (float4*)sLc2;
        #pragma unroll
        for (int e = 0; e < 8; ++e) dst[tid + 256 * e] = src[tid + 256 * e];
        sMu[tid] = mu[tid];
        if (tid < K) sWt[tid] = weights[tid];
    }
    __syncthreads();

    if (tid == 0) {   // log-softmax of weights; zero the finish ticket
        float m = -INFINITY;
        for (int t = 0; t < K; ++t) m = fmaxf(m, sWt[t]);
        float s = 0.0f;
        for (int t = 0; t < K; ++t) s += expf(sWt[t] - m);
        const float lse = m + logf(s);
        for (int t = 0; t < K; ++t) sLogw[t] = sWt[t] - lse;
        *(unsigned int*)(ws + TICKOFF) = 0u;
    }
    __syncthreads();

    if (tid < NPAIR) {
        int tt = tid, pi = 0;
        while (tt >= (K - pi)) { tt -= (K - pi); ++pi; }
        const int pj = pi + tt;
        const float LOG2PI = 1.8378770664093453f;
        float sumlogS = 0.0f, logdetsig = 0.0f;
        #pragma unroll
        for (int r = 0; r < D; ++r) {
            const float di = SLC(pi, r, r), dj = SLC(pj, r, r);
            sumlogS += logf(di + dj);
            logdetsig -= logf(1.0f / di + 1.0f / dj);   // diag(M) = 1/di + 1/dj
        }
        float v[D];
        float quad_acc = 0.0f;
        #pragma unroll
        for (int r = 0; r < D; ++r) {
            const float d0 = sMu[pi * D + r] - sMu[pj * D + r];
            float s = d0;
            #pragma unroll
            for (int b = 0; b < r; ++b)
                s = fmaf(-(SLC(pi, r, b) + SLC(pj, r, b)), v[b], s);
            v[r] = s / (SLC(pi, r, r) + SLC(pj, r, r));
            quad_acc = fmaf(d0, v[r], quad_acc);
        }
        const float quad = -0.5f * quad_acc;
        float c = quad - 0.5f * sumlogS - (float)D * LOG2PI - 0.5f * logdetsig
                  + sLogw[pi] + sLogw[pj];
        if (pi < pj) c += 0.6931471805599453f;   // off-diagonal multiplicity 2
        sCp[tid] = c;
    }
    __syncthreads();
    if (tid == 0) {
        float m = -INFINITY;
        for (int t = 0; t < NPAIR; ++t) m = fmaxf(m, sCp[t]);
        sCmax = m;
        ws[CMAXOFF] = m;
    }
    __syncthreads();
    if (tid < NPAIR)
        ws[C2OFF + tid] = (sCp[tid] - sCmax) * 1.4426950408889634f;
}

// ---------------------------------------------------------------------------
// main v9: 256-thr block = 4 waves covering the SAME 128 samples (S=2/lane).
// Row-group ownership split 4 ways, BALANCED: wave w owns rh-groups {w, 7-w}
// -> exactly 9 c4-units x 32 (row,k) = 288 LDS b128 reads per wave (was
// 512/640 imbalanced 2-way). Grid 1024 blocks x 4 waves = 16 waves/CU
// (4/SIMD) -- double the occupancy of v7/v8 at identical total VALU+LDS
// work. Gram combine in 3 chunks of 12 pairs. Finish kernel folded in via
// device-scope last-block ticket (no spin-wait: deadlock-free).
// ---------------------------------------------------------------------------
__global__ __launch_bounds__(256, 4) void main_kernel(
    const float* __restrict__ X, const float* __restrict__ cst,
    float* __restrict__ partials, float* __restrict__ out,
    unsigned int* __restrict__ ticket, int nsamp, int nblk)
{
    __shared__ __align__(16) float sBig[4864];   // packed M (4608f) / G-exchange
    __shared__ __align__(16) float sW[K * D];
    __shared__ float sC2[NPAIR];
    __shared__ int sIsLast;
    __shared__ float sRed[4];
    const int tid = threadIdx.x;
    const int wv = tid >> 6;        // wave id within block
    const int lane = tid & 63;

    const int n0 = blockIdx.x * 128 + lane;   // all 4 waves: same 128 samples
    const int n1 = n0 + 64;
    const int m0 = (n0 < nsamp) ? n0 : 0;     // branchless clamps
    const int m1 = (n1 < nsamp) ? n1 : 0;

    // x for both samples, column-pair packed (redundant per wave; L1 absorbs)
    v2f xa[16], xb[16];
    {
        const float4* Xv0 = (const float4*)(X + m0 * D);
        const float4* Xv1 = (const float4*)(X + m1 * D);
        #pragma unroll
        for (int q = 0; q < 8; ++q) {
            const float4 t0 = Xv0[q];
            xa[2 * q]     = (v2f){t0.x, t0.y};
            xa[2 * q + 1] = (v2f){t0.z, t0.w};
            const float4 t1 = Xv1[q];
            xb[2 * q]     = (v2f){t1.x, t1.y};
            xb[2 * q + 1] = (v2f){t1.z, t1.w};
        }
    }

    {   // stage packed M + w + c2 into LDS (256 threads)
        const float4* src = (const float4*)cst;
        float4* dst = (float4*)sBig;
        for (int e = tid; e < K * PROWS / 4; e += 256) dst[e] = src[e];
        const float4* srcw = (const float4*)(cst + WOFF);
        float4* dstw = (float4*)sW;
        if (tid < K * D / 4) dstw[tid] = srcw[tid];
        if (tid < NPAIR) sC2[tid] = cst[C2OFF + tid];
    }
    __syncthreads();

    v2f G2[NPAIR];   // this wave's PARTIAL Gram (its 8 rows only)
    #pragma unroll
    for (int t = 0; t < NPAIR; ++t) G2[t] = (v2f){0.0f, 0.0f};

    #pragma unroll
    for (int rh = 0; rh < 8; ++rh) {
        if (((rh < 4) ? rh : 7 - rh) == wv) {   // balanced wave-uniform gate
            #pragma unroll
            for (int rr = 0; rr < 4; ++rr) {
                const int r = 4 * rh + rr;
                v2f ya[K], yb[K];
                #pragma unroll
                for (int k = 0; k < K; ++k) {
                    const float wvv = sW[k * D + r];
                    v2f a0 = (v2f){-wvv, 0.0f};
                    v2f a1 = (v2f){-wvv, 0.0f};
                    const float* Mr = sBig + k * PROWS + proff(r);
                    #pragma unroll
                    for (int c4 = 0; c4 <= rh; ++c4) {
                        const float4 m4 = *(const float4*)(Mr + 4 * c4);
                        const v2f mlo = (v2f){m4.x, m4.y};   // natural reg pairs
                        const v2f mhi = (v2f){m4.z, m4.w};
                        a0 = __builtin_elementwise_fma(mlo, xa[2 * c4],     a0);
                        a1 = __builtin_elementwise_fma(mlo, xb[2 * c4],     a1);
                        a0 = __builtin_elementwise_fma(mhi, xa[2 * c4 + 1], a0);
                        a1 = __builtin_elementwise_fma(mhi, xb[2 * c4 + 1], a1);
                    }
                    ya[k] = a0;  yb[k] = a1;
                }
                v2f y2[K];
                #pragma unroll
                for (int k = 0; k < K; ++k)
                    y2[k] = (v2f){ya[k].x + ya[k].y, yb[k].x + yb[k].y};
                #pragma unroll
                for (int pi = 0; pi < K; ++pi)
                    #pragma unroll
                    for (int pj = pi; pj < K; ++pj)
                        G2[gidx(pi, pj)] = __builtin_elementwise_fma(
                            y2[pi], y2[pj], G2[gidx(pi, pj)]);
            }
        }
    }

    __syncthreads();   // all M reads complete; sBig reusable for exchange

    // chunked 4-way combine: 3 chunks x 12 pairs; waves 1-3 publish, wave 0 sums
    {
        float2* xch = (float2*)sBig;   // [3 waves x 12 pairs][64 lanes]
        #pragma unroll
        for (int chunk = 0; chunk < 3; ++chunk) {
            if (wv > 0) {
                #pragma unroll
                for (int t = 0; t < 12; ++t)
                    xch[((wv - 1) * 12 + t) * 64 + lane] =
                        make_float2(G2[chunk * 12 + t].x, G2[chunk * 12 + t].y);
            }
            __syncthreads();
            if (wv == 0) {
                #pragma unroll
                for (int t = 0; t < 12; ++t) {
                    const float2 g0 = xch[(0 * 12 + t) * 64 + lane];
                    const float2 g1 = xch[(1 * 12 + t) * 64 + lane];
                    const float2 g2 = xch[(2 * 12 + t) * 64 + lane];
                    G2[chunk * 12 + t] +=
                        (v2f){g0.x + g1.x + g2.x, g0.y + g1.y + g2.y};
                }
            }
            __syncthreads();
        }
    }

    // wave 0: 36-term exp sum for both samples, reduce, store + ticket
    if (wv == 0) {
        v2f acc2 = (v2f){0.0f, 0.0f};
        const float NH = -0.72134752044448170f;   // -0.5*log2(e)
        #pragma unroll
        for (int pi = 0; pi < K; ++pi)
            #pragma unroll
            for (int pj = pi; pj < K; ++pj) {
                const v2f q2 = __builtin_elementwise_fma(
                    (v2f){2.0f, 2.0f}, G2[gidx(pi, pj)],
                    G2[gidx(pi, pi)] + G2[gidx(pj, pj)]);
                const float c = sC2[gidx(pi, pj)];
                const v2f e2 = __builtin_elementwise_fma((v2f){NH, NH}, q2,
                                                         (v2f){c, c});
                acc2.x += exp2f(e2.x);
                acc2.y += exp2f(e2.y);
            }
        float acc = ((n0 < nsamp) ? acc2.x : 0.0f)
                  + ((n1 < nsamp) ? acc2.y : 0.0f);

        #pragma unroll
        for (int s = 1; s < 64; s <<= 1) acc += __shfl_xor(acc, s, 64);
        if (lane == 0) {
            partials[blockIdx.x] = acc;
            __threadfence();                          // release partial
            const unsigned prev = atomicAdd(ticket, 1u);   // device scope (G12)
            sIsLast = (prev == (unsigned)(nblk - 1)) ? 1 : 0;
        }
    }
    __syncthreads();

    // last block to finish performs the final reduction (was finish_kernel)
    if (sIsLast) {
        __threadfence();                              // acquire partials
        float a2 = 0.0f;
        for (int e = tid; e < nblk; e += 256) a2 += partials[e];
        #pragma unroll
        for (int s = 1; s < 64; s <<= 1) a2 += __shfl_xor(a2, s, 64);
        if (lane == 0) sRed[wv] = a2;
        __syncthreads();
        if (tid == 0)
            out[0] = cst[CMAXOFF]
                   + logf(sRed[0] + sRed[1] + sRed[2] + sRed[3]);
    }
}

extern "C" void kernel_launch(void* const* d_in, const int* in_sizes, int n_in,
                              void* d_out, int out_size, void* d_ws, size_t ws_size,
                              hipStream_t stream) {
    const float* X = (const float*)d_in[0];
    const float* mu = (const float*)d_in[1];
    const float* L = (const float*)d_in[2];
    const float* w = (const float*)d_in[3];
    float* wsf = (float*)d_ws;
    float* out = (float*)d_out;

    const int nsamp = in_sizes[0] / D;
    const int nblk = (nsamp + 127) / 128;   // 128 samples per 4-wave block

    setup1_kernel<<<K, 64, 0, stream>>>(mu, L, wsf);
    setup2_kernel<<<1, 256, 0, stream>>>(mu, w, wsf);
    main_kernel<<<nblk, 256, 0, stream>>>(X, wsf, wsf + PARTOFF, out,
                                          (unsigned int*)(wsf + TICKOFF),
                                          nsamp, nblk);
}

// Round 4
// 172.077 us; speedup vs baseline: 2.0959x; 2.0959x over previous
//
#include <hip/hip_runtime.h>

// Problem constants
#define D 32
#define K 8
#define NPAIR 36
#define PROWS 576              // packed (4-padded triangular) floats per matrix

// ws layout (float offsets)
#define PMOFF 0                // packed invLc, 8 x 576
#define WOFF 4608              // w_k = invLc_k mu_k, 8 x 32
#define C2OFF 4864             // (c'_t - cmax) * log2(e), 36
#define CMAXOFF 4900
#define TICKOFF 4904           // last-block ticket (unsigned), zeroed by setup2
#define LCOFF 4928             // Lc (cholesky factors), 8 x 32 x 32, upper zeroed
#define PARTOFF 13120          // per-block partial sums (<=1024)

typedef float v2f __attribute__((ext_vector_type(2)));

__host__ __device__ constexpr int gidx(int i, int j) {  // i<=j packed pair index
    return i * 8 + j - i * (i + 1) / 2;
}
__host__ __device__ constexpr int proff(int r) {        // packed row offset
    return 4 * (r / 4 + 1) * (2 * (r / 4) + (r % 4));
}

// ---------------------------------------------------------------------------
// setup1 (R0 verbatim, 8 parallel blocks -- one CU per cluster): spill-free,
// invLc column solve keeps state in LDS.
// ---------------------------------------------------------------------------
__global__ __launch_bounds__(64) void setup1_kernel(
    const float* __restrict__ mu, const float* __restrict__ L,
    float* __restrict__ ws)
{
    __shared__ float sA[D][D + 1];
    __shared__ float sLc[D][D + 1];
    __shared__ float sI[D][D + 1];
    const int k = blockIdx.x;
    const int tid = threadIdx.x;
    const int i = tid & 31;

    for (int e = tid; e < D * D; e += 64) sI[e >> 5][e & 31] = L[k * D * D + e];
    __syncthreads();

    for (int e = tid; e < D * D; e += 64) {
        const int a = e >> 5, c = e & 31;
        float s = (a == c) ? 1.0f : 0.0f;
        #pragma unroll
        for (int b = 0; b < D; ++b) s = fmaf(sI[a][b], sI[c][b], s);
        sA[a][c] = s;
    }
    __syncthreads();

    float lrow[D];
    #pragma unroll
    for (int j = 0; j < D; ++j) {
        if (i == j) {
            float s = sA[j][j];
            #pragma unroll
            for (int b = 0; b < j; ++b) s = fmaf(-lrow[b], lrow[b], s);
            const float d = sqrtf(s);
            lrow[j] = d;
            #pragma unroll
            for (int b = 0; b < j; ++b) sLc[j][b] = lrow[b];
            sLc[j][j] = d;
        }
        __syncthreads();
        if (i > j) {
            float s = sA[i][j];
            #pragma unroll
            for (int b = 0; b < j; ++b) s = fmaf(-lrow[b], sLc[j][b], s);
            lrow[j] = s / sLc[j][j];
        }
    }
    __syncthreads();

    for (int e = tid; e < D * D; e += 64) {
        const int r = e >> 5, c = e & 31;
        ws[LCOFF + k * D * D + e] = (c <= r) ? sLc[r][c] : 0.0f;
    }

    {
        const int j = i;
        #pragma unroll
        for (int ii = 0; ii < D; ++ii) {
            float s = (ii == j) ? 1.0f : 0.0f;
            #pragma unroll
            for (int b = 0; b < ii; ++b) s = fmaf(-sLc[ii][b], sI[b][j], s);
            const float cii = s / sLc[ii][ii];
            sI[ii][j] = cii;
            const int w4 = 4 * (ii / 4 + 1);
            if (j < w4) ws[PMOFF + k * PROWS + proff(ii) + j] = cii;
        }
    }
    __syncthreads();

    {
        float s = 0.0f;
        #pragma unroll
        for (int b = 0; b < D; ++b) s = fmaf(sI[i][b], mu[k * D + b], s);
        ws[WOFF + k * D + i] = s;
    }
}

// ---------------------------------------------------------------------------
// setup2 (R0 verbatim + ticket zero): 256-thread block, all inputs staged to
// LDS before the 36-thread solve.
// ---------------------------------------------------------------------------
#define SLC(kk, r, c) sLc2[(kk) * 1024 + (r) * 32 + (c)]

__global__ __launch_bounds__(256) void setup2_kernel(
    const float* __restrict__ mu, const float* __restrict__ weights,
    float* __restrict__ ws)
{
    __shared__ float sLc2[K * D * D];   // 32 KB
    __shared__ float sMu[K * D];
    __shared__ float sWt[K];
    __shared__ float sLogw[K];
    __shared__ float sCp[NPAIR];
    __shared__ float sCmax;
    const int tid = threadIdx.x;

    {   // stage everything: 8 float4/thread for Lc, 1 float/thread for mu
        const float4* src = (const float4*)(ws + LCOFF);
        float4* dst = (float4*)sLc2;
        #pragma unroll
        for (int e = 0; e < 8; ++e) dst[tid + 256 * e] = src[tid + 256 * e];
        sMu[tid] = mu[tid];
        if (tid < K) sWt[tid] = weights[tid];
    }
    __syncthreads();

    if (tid == 0) {   // log-softmax of weights; zero the finish ticket
        float m = -INFINITY;
        for (int t = 0; t < K; ++t) m = fmaxf(m, sWt[t]);
        float s = 0.0f;
        for (int t = 0; t < K; ++t) s += expf(sWt[t] - m);
        const float lse = m + logf(s);
        for (int t = 0; t < K; ++t) sLogw[t] = sWt[t] - lse;
        *(unsigned int*)(ws + TICKOFF) = 0u;
    }
    __syncthreads();

    if (tid < NPAIR) {
        int tt = tid, pi = 0;
        while (tt >= (K - pi)) { tt -= (K - pi); ++pi; }
        const int pj = pi + tt;
        const float LOG2PI = 1.8378770664093453f;
        float sumlogS = 0.0f, logdetsig = 0.0f;
        #pragma unroll
        for (int r = 0; r < D; ++r) {
            const float di = SLC(pi, r, r), dj = SLC(pj, r, r);
            sumlogS += logf(di + dj);
            logdetsig -= logf(1.0f / di + 1.0f / dj);   // diag(M) = 1/di + 1/dj
        }
        float v[D];
        float quad_acc = 0.0f;
        #pragma unroll
        for (int r = 0; r < D; ++r) {
            const float d0 = sMu[pi * D + r] - sMu[pj * D + r];
            float s = d0;
            #pragma unroll
            for (int b = 0; b < r; ++b)
                s = fmaf(-(SLC(pi, r, b) + SLC(pj, r, b)), v[b], s);
            v[r] = s / (SLC(pi, r, r) + SLC(pj, r, r));
            quad_acc = fmaf(d0, v[r], quad_acc);
        }
        const float quad = -0.5f * quad_acc;
        float c = quad - 0.5f * sumlogS - (float)D * LOG2PI - 0.5f * logdetsig
                  + sLogw[pi] + sLogw[pj];
        if (pi < pj) c += 0.6931471805599453f;   // off-diagonal multiplicity 2
        sCp[tid] = c;
    }
    __syncthreads();
    if (tid == 0) {
        float m = -INFINITY;
        for (int t = 0; t < NPAIR; ++t) m = fmaxf(m, sCp[t]);
        sCmax = m;
        ws[CMAXOFF] = m;
    }
    __syncthreads();
    if (tid < NPAIR)
        ws[C2OFF + tid] = (sCp[tid] - sCmax) * 1.4426950408889634f;
}

// ---------------------------------------------------------------------------
// main v10: v7's proven 2-wave/128-sample shape, but M/w/c2 come STRAIGHT
// FROM GLOBAL with wave-uniform addresses -> compiler scalarizes to s_load
// through the scalar cache (separate pipe). This removes the ds_read_b128
// broadcast bottleneck (1152 reads x 12cyc x 16 useful B = the 23us/CU LDS
// floor that capped v7 at 52us, VALUBusy 23%). x is packed ACROSS samples
// ({x_s0[c], x_s1[c]}) so the scalar M value feeds both v2f halves and the
// per-row horizontal fold disappears. LDS = 18.7KB exchange buffer only.
// Finish folded in via last-block ticket (no spin-wait).
// ---------------------------------------------------------------------------
__global__ __launch_bounds__(128, 2) void main_kernel(
    const float* __restrict__ X, const float* __restrict__ cst,
    float* __restrict__ partials, float* __restrict__ out,
    unsigned int* __restrict__ ticket, int nsamp, int nblk)
{
    __shared__ __align__(16) float2 sXch[NPAIR * 65];   // Gram exchange, 18.7 KB
    __shared__ int sIsLast;
    __shared__ float sRed[2];
    const int tid = threadIdx.x;
    const int wv = tid >> 6;        // wave id within block
    const int lane = tid & 63;

    const int n0 = blockIdx.x * 128 + lane;
    const int n1 = n0 + 64;
    const int m0 = (n0 < nsamp) ? n0 : 0;     // branchless clamps
    const int m1 = (n1 < nsamp) ? n1 : 0;

    // x for both samples, packed ACROSS samples: xs[c] = {x_s0[c], x_s1[c]}
    v2f xs[D];
    {
        const float4* Xv0 = (const float4*)(X + m0 * D);
        const float4* Xv1 = (const float4*)(X + m1 * D);
        #pragma unroll
        for (int q = 0; q < 8; ++q) {
            const float4 t0 = Xv0[q];
            const float4 t1 = Xv1[q];
            xs[4 * q + 0] = (v2f){t0.x, t1.x};
            xs[4 * q + 1] = (v2f){t0.y, t1.y};
            xs[4 * q + 2] = (v2f){t0.z, t1.z};
            xs[4 * q + 3] = (v2f){t0.w, t1.w};
        }
    }

    v2f G2[NPAIR];   // this wave's PARTIAL Gram (rows with rh%2 == wv)
    #pragma unroll
    for (int t = 0; t < NPAIR; ++t) G2[t] = (v2f){0.0f, 0.0f};

    #pragma unroll
    for (int rh = 0; rh < 8; ++rh) {
        if ((rh & 1) == wv) {               // wave-uniform gate
            #pragma unroll
            for (int rr = 0; rr < 4; ++rr) {
                const int r = 4 * rh + rr;
                v2f y2[K];
                #pragma unroll
                for (int k = 0; k < K; ++k) {
                    const float wvv = cst[WOFF + k * D + r];   // uniform -> s_load
                    v2f a = (v2f){-wvv, -wvv};
                    const float* Mr = cst + k * PROWS + proff(r);  // uniform base
                    #pragma unroll
                    for (int c4 = 0; c4 <= rh; ++c4) {
                        const float4 m4 = *(const float4*)(Mr + 4 * c4); // s_load_dwordx4
                        a = __builtin_elementwise_fma((v2f){m4.x, m4.x},
                                                      xs[4 * c4 + 0], a);
                        a = __builtin_elementwise_fma((v2f){m4.y, m4.y},
                                                      xs[4 * c4 + 1], a);
                        a = __builtin_elementwise_fma((v2f){m4.z, m4.z},
                                                      xs[4 * c4 + 2], a);
                        a = __builtin_elementwise_fma((v2f){m4.w, m4.w},
                                                      xs[4 * c4 + 3], a);
                    }
                    y2[k] = a;   // already {y_s0, y_s1} -- no horizontal fold
                }
                #pragma unroll
                for (int pi = 0; pi < K; ++pi)
                    #pragma unroll
                    for (int pj = pi; pj < K; ++pj)
                        G2[gidx(pi, pj)] = __builtin_elementwise_fma(
                            y2[pi], y2[pj], G2[gidx(pi, pj)]);
            }
        }
    }

    __syncthreads();

    // wave 1 publishes partial Gram: float2 element at index t*65 + lane
    if (wv == 1) {
        #pragma unroll
        for (int t = 0; t < NPAIR; ++t)
            sXch[t * 65 + lane] = make_float2(G2[t].x, G2[t].y);
    }
    __syncthreads();

    // wave 0: combine, 36-term exp sum for both samples, reduce, store
    if (wv == 0) {
        #pragma unroll
        for (int t = 0; t < NPAIR; ++t) {
            const float2 g = sXch[t * 65 + lane];
            G2[t] += (v2f){g.x, g.y};
        }

        v2f acc2 = (v2f){0.0f, 0.0f};
        const float NH = -0.72134752044448170f;   // -0.5*log2(e)
        #pragma unroll
        for (int pi = 0; pi < K; ++pi)
            #pragma unroll
            for (int pj = pi; pj < K; ++pj) {
                const v2f q2 = __builtin_elementwise_fma(
                    (v2f){2.0f, 2.0f}, G2[gidx(pi, pj)],
                    G2[gidx(pi, pi)] + G2[gidx(pj, pj)]);
                const float c = cst[C2OFF + gidx(pi, pj)];   // uniform -> s_load
                const v2f e2 = __builtin_elementwise_fma((v2f){NH, NH}, q2,
                                                         (v2f){c, c});
                acc2.x += exp2f(e2.x);
                acc2.y += exp2f(e2.y);
            }
        float acc = ((n0 < nsamp) ? acc2.x : 0.0f)
                  + ((n1 < nsamp) ? acc2.y : 0.0f);

        #pragma unroll
        for (int s = 1; s < 64; s <<= 1) acc += __shfl_xor(acc, s, 64);
        if (lane == 0) {
            partials[blockIdx.x] = acc;
            __threadfence();                          // release partial
            const unsigned prev = atomicAdd(ticket, 1u);   // device scope (G12)
            sIsLast = (prev == (unsigned)(nblk - 1)) ? 1 : 0;
        }
    }
    __syncthreads();

    // last block to finish performs the final reduction (was finish_kernel)
    if (sIsLast) {
        __threadfence();                              // acquire partials
        float a2 = 0.0f;
        for (int e = tid; e < nblk; e += 128) a2 += partials[e];
        #pragma unroll
        for (int s = 1; s < 64; s <<= 1) a2 += __shfl_xor(a2, s, 64);
        if (lane == 0) sRed[wv] = a2;
        __syncthreads();
        if (tid == 0) out[0] = cst[CMAXOFF] + logf(sRed[0] + sRed[1]);
    }
}

extern "C" void kernel_launch(void* const* d_in, const int* in_sizes, int n_in,
                              void* d_out, int out_size, void* d_ws, size_t ws_size,
                              hipStream_t stream) {
    const float* X = (const float*)d_in[0];
    const float* mu = (const float*)d_in[1];
    const float* L = (const float*)d_in[2];
    const float* w = (const float*)d_in[3];
    float* wsf = (float*)d_ws;
    float* out = (float*)d_out;

    const int nsamp = in_sizes[0] / D;
    const int nblk = (nsamp + 127) / 128;   // 128 samples per 2-wave block

    setup1_kernel<<<K, 64, 0, stream>>>(mu, L, wsf);
    setup2_kernel<<<1, 256, 0, stream>>>(mu, w, wsf);
    main_kernel<<<nblk, 128, 0, stream>>>(X, wsf, wsf + PARTOFF, out,
                                          (unsigned int*)(wsf + TICKOFF),
                                          nsamp, nblk);
}

// Round 5
// 159.838 us; speedup vs baseline: 2.2564x; 1.0766x over previous
//
#include <hip/hip_runtime.h>

// Problem constants
#define D 32
#define K 8
#define NPAIR 36
#define PROWS 576              // packed (4-padded triangular) floats per matrix

// ws layout (float offsets)
#define PMOFF 0                // packed invLc, 8 x 576
#define WOFF 4608              // w_k = invLc_k mu_k, 8 x 32
#define C2OFF 4864             // (c'_t - cmax) * log2(e), 36
#define CMAXOFF 4900
#define TICKOFF 4904           // last-block ticket (unsigned), zeroed by setup2
#define LCOFF 4928             // Lc (cholesky factors), 8 x 32 x 32, upper zeroed
#define PARTOFF 13120          // per-block partial sums (<=1024)

typedef float v2f __attribute__((ext_vector_type(2)));

__host__ __device__ constexpr int gidx(int i, int j) {  // i<=j packed pair index
    return i * 8 + j - i * (i + 1) / 2;
}
__host__ __device__ constexpr int proff(int r) {        // packed row offset
    return 4 * (r / 4 + 1) * (2 * (r / 4) + (r % 4));
}

// ---------------------------------------------------------------------------
// setup1 (R0 verbatim, 8 parallel blocks -- one CU per cluster)
// ---------------------------------------------------------------------------
__global__ __launch_bounds__(64) void setup1_kernel(
    const float* __restrict__ mu, const float* __restrict__ L,
    float* __restrict__ ws)
{
    __shared__ float sA[D][D + 1];
    __shared__ float sLc[D][D + 1];
    __shared__ float sI[D][D + 1];
    const int k = blockIdx.x;
    const int tid = threadIdx.x;
    const int i = tid & 31;

    for (int e = tid; e < D * D; e += 64) sI[e >> 5][e & 31] = L[k * D * D + e];
    __syncthreads();

    for (int e = tid; e < D * D; e += 64) {
        const int a = e >> 5, c = e & 31;
        float s = (a == c) ? 1.0f : 0.0f;
        #pragma unroll
        for (int b = 0; b < D; ++b) s = fmaf(sI[a][b], sI[c][b], s);
        sA[a][c] = s;
    }
    __syncthreads();

    float lrow[D];
    #pragma unroll
    for (int j = 0; j < D; ++j) {
        if (i == j) {
            float s = sA[j][j];
            #pragma unroll
            for (int b = 0; b < j; ++b) s = fmaf(-lrow[b], lrow[b], s);
            const float d = sqrtf(s);
            lrow[j] = d;
            #pragma unroll
            for (int b = 0; b < j; ++b) sLc[j][b] = lrow[b];
            sLc[j][j] = d;
        }
        __syncthreads();
        if (i > j) {
            float s = sA[i][j];
            #pragma unroll
            for (int b = 0; b < j; ++b) s = fmaf(-lrow[b], sLc[j][b], s);
            lrow[j] = s / sLc[j][j];
        }
    }
    __syncthreads();

    for (int e = tid; e < D * D; e += 64) {
        const int r = e >> 5, c = e & 31;
        ws[LCOFF + k * D * D + e] = (c <= r) ? sLc[r][c] : 0.0f;
    }

    {
        const int j = i;
        #pragma unroll
        for (int ii = 0; ii < D; ++ii) {
            float s = (ii == j) ? 1.0f : 0.0f;
            #pragma unroll
            for (int b = 0; b < ii; ++b) s = fmaf(-sLc[ii][b], sI[b][j], s);
            const float cii = s / sLc[ii][ii];
            sI[ii][j] = cii;
            const int w4 = 4 * (ii / 4 + 1);
            if (j < w4) ws[PMOFF + k * PROWS + proff(ii) + j] = cii;
        }
    }
    __syncthreads();

    {
        float s = 0.0f;
        #pragma unroll
        for (int b = 0; b < D; ++b) s = fmaf(sI[i][b], mu[k * D + b], s);
        ws[WOFF + k * D + i] = s;
    }
}

// ---------------------------------------------------------------------------
// setup2 (R0 verbatim + ticket zero)
// ---------------------------------------------------------------------------
#define SLC(kk, r, c) sLc2[(kk) * 1024 + (r) * 32 + (c)]

__global__ __launch_bounds__(256) void setup2_kernel(
    const float* __restrict__ mu, const float* __restrict__ weights,
    float* __restrict__ ws)
{
    __shared__ float sLc2[K * D * D];   // 32 KB
    __shared__ float sMu[K * D];
    __shared__ float sWt[K];
    __shared__ float sLogw[K];
    __shared__ float sCp[NPAIR];
    __shared__ float sCmax;
    const int tid = threadIdx.x;

    {   // stage everything: 8 float4/thread for Lc, 1 float/thread for mu
        const float4* src = (const float4*)(ws + LCOFF);
        float4* dst = (float4*)sLc2;
        #pragma unroll
        for (int e = 0; e < 8; ++e) dst[tid + 256 * e] = src[tid + 256 * e];
        sMu[tid] = mu[tid];
        if (tid < K) sWt[tid] = weights[tid];
    }
    __syncthreads();

    if (tid == 0) {   // log-softmax of weights; zero the finish ticket
        float m = -INFINITY;
        for (int t = 0; t < K; ++t) m = fmaxf(m, sWt[t]);
        float s = 0.0f;
        for (int t = 0; t < K; ++t) s += expf(sWt[t] - m);
        const float lse = m + logf(s);
        for (int t = 0; t < K; ++t) sLogw[t] = sWt[t] - lse;
        *(unsigned int*)(ws + TICKOFF) = 0u;
    }
    __syncthreads();

    if (tid < NPAIR) {
        int tt = tid, pi = 0;
        while (tt >= (K - pi)) { tt -= (K - pi); ++pi; }
        const int pj = pi + tt;
        const float LOG2PI = 1.8378770664093453f;
        float sumlogS = 0.0f, logdetsig = 0.0f;
        #pragma unroll
        for (int r = 0; r < D; ++r) {
            const float di = SLC(pi, r, r), dj = SLC(pj, r, r);
            sumlogS += logf(di + dj);
            logdetsig -= logf(1.0f / di + 1.0f / dj);   // diag(M) = 1/di + 1/dj
        }
        float v[D];
        float quad_acc = 0.0f;
        #pragma unroll
        for (int r = 0; r < D; ++r) {
            const float d0 = sMu[pi * D + r] - sMu[pj * D + r];
            float s = d0;
            #pragma unroll
            for (int b = 0; b < r; ++b)
                s = fmaf(-(SLC(pi, r, b) + SLC(pj, r, b)), v[b], s);
            v[r] = s / (SLC(pi, r, r) + SLC(pj, r, r));
            quad_acc = fmaf(d0, v[r], quad_acc);
        }
        const float quad = -0.5f * quad_acc;
        float c = quad - 0.5f * sumlogS - (float)D * LOG2PI - 0.5f * logdetsig
                  + sLogw[pi] + sLogw[pj];
        if (pi < pj) c += 0.6931471805599453f;   // off-diagonal multiplicity 2
        sCp[tid] = c;
    }
    __syncthreads();
    if (tid == 0) {
        float m = -INFINITY;
        for (int t = 0; t < NPAIR; ++t) m = fmaxf(m, sCp[t]);
        sCmax = m;
        ws[CMAXOFF] = m;
    }
    __syncthreads();
    if (tid < NPAIR)
        ws[C2OFF + tid] = (sCp[tid] - sCmax) * 1.4426950408889634f;
}

// ---------------------------------------------------------------------------
// main v11: v9's 4-wave/128-sample balanced row split (wave w owns rh-groups
// {w, 7-w} = 288 LDS b128 each) with the R3 spill bug fixed: launch_bounds
// (256, 2) -> VGPR cap 256, compiler lands ~110-130 (R1/R4 precedent), which
// permits 4 waves/SIMD. Grid 1024 x 4 waves = 16 waves/CU, 2x v7's
// latency hiding at identical total LDS+VALU work. Plus v10's across-sample
// packing xs[c] = {x_s0[c], x_s1[c]}: removes the per-row horizontal fold
// and ya/yb registers; M splat to both halves is free via pk op_sel.
// M/w/c2 from LDS (proven pipe). Finish folded in via last-block ticket.
// ---------------------------------------------------------------------------
__global__ __launch_bounds__(256, 2) void main_kernel(
    const float* __restrict__ X, const float* __restrict__ cst,
    float* __restrict__ partials, float* __restrict__ out,
    unsigned int* __restrict__ ticket, int nsamp, int nblk)
{
    __shared__ __align__(16) float sBig[4864];   // packed M (4608f) / G-exchange
    __shared__ __align__(16) float sW[K * D];
    __shared__ float sC2[NPAIR];
    __shared__ int sIsLast;
    __shared__ float sRed[4];
    const int tid = threadIdx.x;
    const int wv = tid >> 6;        // wave id within block
    const int lane = tid & 63;

    const int n0 = blockIdx.x * 128 + lane;   // all 4 waves: same 128 samples
    const int n1 = n0 + 64;
    const int m0 = (n0 < nsamp) ? n0 : 0;     // branchless clamps
    const int m1 = (n1 < nsamp) ? n1 : 0;

    // x for both samples, packed ACROSS samples: xs[c] = {x_s0[c], x_s1[c]}
    v2f xs[D];
    {
        const float4* Xv0 = (const float4*)(X + m0 * D);
        const float4* Xv1 = (const float4*)(X + m1 * D);
        #pragma unroll
        for (int q = 0; q < 8; ++q) {
            const float4 t0 = Xv0[q];
            const float4 t1 = Xv1[q];
            xs[4 * q + 0] = (v2f){t0.x, t1.x};
            xs[4 * q + 1] = (v2f){t0.y, t1.y};
            xs[4 * q + 2] = (v2f){t0.z, t1.z};
            xs[4 * q + 3] = (v2f){t0.w, t1.w};
        }
    }

    {   // stage packed M + w + c2 into LDS (256 threads)
        const float4* src = (const float4*)cst;
        float4* dst = (float4*)sBig;
        for (int e = tid; e < K * PROWS / 4; e += 256) dst[e] = src[e];
        const float4* srcw = (const float4*)(cst + WOFF);
        float4* dstw = (float4*)sW;
        if (tid < K * D / 4) dstw[tid] = srcw[tid];
        if (tid < NPAIR) sC2[tid] = cst[C2OFF + tid];
    }
    __syncthreads();

    v2f G2[NPAIR];   // this wave's PARTIAL Gram (its 8 rows only)
    #pragma unroll
    for (int t = 0; t < NPAIR; ++t) G2[t] = (v2f){0.0f, 0.0f};

    #pragma unroll
    for (int rh = 0; rh < 8; ++rh) {
        if (((rh < 4) ? rh : 7 - rh) == wv) {   // balanced wave-uniform gate
            #pragma unroll
            for (int rr = 0; rr < 4; ++rr) {
                const int r = 4 * rh + rr;
                v2f y2[K];
                #pragma unroll
                for (int k = 0; k < K; ++k) {
                    const float wvv = sW[k * D + r];
                    v2f a = (v2f){-wvv, -wvv};
                    const float* Mr = sBig + k * PROWS + proff(r);
                    #pragma unroll
                    for (int c4 = 0; c4 <= rh; ++c4) {
                        const float4 m4 = *(const float4*)(Mr + 4 * c4); // b128
                        a = __builtin_elementwise_fma((v2f){m4.x, m4.x},
                                                      xs[4 * c4 + 0], a);
                        a = __builtin_elementwise_fma((v2f){m4.y, m4.y},
                                                      xs[4 * c4 + 1], a);
                        a = __builtin_elementwise_fma((v2f){m4.z, m4.z},
                                                      xs[4 * c4 + 2], a);
                        a = __builtin_elementwise_fma((v2f){m4.w, m4.w},
                                                      xs[4 * c4 + 3], a);
                    }
                    y2[k] = a;   // already {y_s0, y_s1} -- no horizontal fold
                }
                #pragma unroll
                for (int pi = 0; pi < K; ++pi)
                    #pragma unroll
                    for (int pj = pi; pj < K; ++pj)
                        G2[gidx(pi, pj)] = __builtin_elementwise_fma(
                            y2[pi], y2[pj], G2[gidx(pi, pj)]);
            }
        }
    }

    __syncthreads();   // all M reads complete; sBig reusable for exchange

    // chunked 4-way combine: 3 chunks x 12 pairs; waves 1-3 publish, wave 0 sums
    {
        float2* xch = (float2*)sBig;   // [3 waves x 12 pairs][64 lanes]
        #pragma unroll
        for (int chunk = 0; chunk < 3; ++chunk) {
            if (wv > 0) {
                #pragma unroll
                for (int t = 0; t < 12; ++t)
                    xch[((wv - 1) * 12 + t) * 64 + lane] =
                        make_float2(G2[chunk * 12 + t].x, G2[chunk * 12 + t].y);
            }
            __syncthreads();
            if (wv == 0) {
                #pragma unroll
                for (int t = 0; t < 12; ++t) {
                    const float2 g0 = xch[(0 * 12 + t) * 64 + lane];
                    const float2 g1 = xch[(1 * 12 + t) * 64 + lane];
                    const float2 g2 = xch[(2 * 12 + t) * 64 + lane];
                    G2[chunk * 12 + t] +=
                        (v2f){g0.x + g1.x + g2.x, g0.y + g1.y + g2.y};
                }
            }
            __syncthreads();
        }
    }

    // wave 0: 36-term exp sum for both samples, reduce, store + ticket
    if (wv == 0) {
        v2f acc2 = (v2f){0.0f, 0.0f};
        const float NH = -0.72134752044448170f;   // -0.5*log2(e)
        #pragma unroll
        for (int pi = 0; pi < K; ++pi)
            #pragma unroll
            for (int pj = pi; pj < K; ++pj) {
                const v2f q2 = __builtin_elementwise_fma(
                    (v2f){2.0f, 2.0f}, G2[gidx(pi, pj)],
                    G2[gidx(pi, pi)] + G2[gidx(pj, pj)]);
                const float c = sC2[gidx(pi, pj)];
                const v2f e2 = __builtin_elementwise_fma((v2f){NH, NH}, q2,
                                                         (v2f){c, c});
                acc2.x += exp2f(e2.x);
                acc2.y += exp2f(e2.y);
            }
        float acc = ((n0 < nsamp) ? acc2.x : 0.0f)
                  + ((n1 < nsamp) ? acc2.y : 0.0f);

        #pragma unroll
        for (int s = 1; s < 64; s <<= 1) acc += __shfl_xor(acc, s, 64);
        if (lane == 0) {
            partials[blockIdx.x] = acc;
            __threadfence();                          // release partial
            const unsigned prev = atomicAdd(ticket, 1u);   // device scope (G12)
            sIsLast = (prev == (unsigned)(nblk - 1)) ? 1 : 0;
        }
    }
    __syncthreads();

    // last block to finish performs the final reduction (was finish_kernel)
    if (sIsLast) {
        __threadfence();                              // acquire partials
        float a2 = 0.0f;
        for (int e = tid; e < nblk; e += 256) a2 += partials[e];
        #pragma unroll
        for (int s = 1; s < 64; s <<= 1) a2 += __shfl_xor(a2, s, 64);
        if (lane == 0) sRed[wv] = a2;
        __syncthreads();
        if (tid == 0)
            out[0] = cst[CMAXOFF]
                   + logf(sRed[0] + sRed[1] + sRed[2] + sRed[3]);
    }
}

extern "C" void kernel_launch(void* const* d_in, const int* in_sizes, int n_in,
                              void* d_out, int out_size, void* d_ws, size_t ws_size,
                              hipStream_t stream) {
    const float* X = (const float*)d_in[0];
    const float* mu = (const float*)d_in[1];
    const float* L = (const float*)d_in[2];
    const float* w = (const float*)d_in[3];
    float* wsf = (float*)d_ws;
    float* out = (float*)d_out;

    const int nsamp = in_sizes[0] / D;
    const int nblk = (nsamp + 127) / 128;   // 128 samples per 4-wave block

    setup1_kernel<<<K, 64, 0, stream>>>(mu, L, wsf);
    setup2_kernel<<<1, 256, 0, stream>>>(mu, w, wsf);
    main_kernel<<<nblk, 256, 0, stream>>>(X, wsf, wsf + PARTOFF, out,
                                          (unsigned int*)(wsf + TICKOFF),
                                          nsamp, nblk);
}

// Round 6
// 151.088 us; speedup vs baseline: 2.3871x; 1.0579x over previous
//
#include <hip/hip_runtime.h>

// Problem constants
#define D 32
#define K 8
#define NPAIR 36

// ws layout (float offsets)
#define AFROFF 0        // A-fragments bf16 hi/lo: 8k x 4KB = 32 KB (8192 floats)
#define WFROFF 8192     // -w in C-frag order: [k][half][16] = 256 floats
#define C2OFF 8448      // (c'_t - cmax) * log2(e), 36
#define CMAXOFF 8484
#define TICKOFF 8488    // last-block ticket (unsigned), zeroed by setup2
#define LCOFF 8512      // Lc (cholesky factors), 8 x 32 x 32
#define PARTOFF 16704   // per-block partial sums (<=1024)

typedef short s16x8 __attribute__((ext_vector_type(8)));    // 8 bf16 (4 VGPR)
typedef float f32x16 __attribute__((ext_vector_type(16)));  // MFMA 32x32 acc

union FragU { uint4 u4; s16x8 s8; };

__host__ __device__ constexpr int gidx(int i, int j) {  // i<=j packed pair index
    return i * 8 + j - i * (i + 1) / 2;
}

// f32 -> bf16 (RNE) and back, via bit ops (no __bf16 type dependence)
static __device__ inline unsigned short f2bf(float v) {
    union { float f; unsigned u; } c; c.f = v;
    unsigned r = (c.u + 0x7FFFu + ((c.u >> 16) & 1u)) >> 16;
    return (unsigned short)r;
}
static __device__ inline float bf2f(unsigned short h) {
    union { unsigned u; float f; } c; c.u = ((unsigned)h) << 16;
    return c.f;
}

// pack 8 floats (v[0..7]) into hi/lo bf16x8 (as uint4 bit patterns)
static __device__ inline void pack8(const float* v, uint4& hi, uint4& lo) {
    unsigned hw[4], lw[4];
    #pragma unroll
    for (int p = 0; p < 4; ++p) {
        const unsigned short h0 = f2bf(v[2 * p]);
        const unsigned short h1 = f2bf(v[2 * p + 1]);
        hw[p] = (unsigned)h0 | ((unsigned)h1 << 16);
        lw[p] = (unsigned)f2bf(v[2 * p] - bf2f(h0))
              | ((unsigned)f2bf(v[2 * p + 1] - bf2f(h1)) << 16);
    }
    hi = make_uint4(hw[0], hw[1], hw[2], hw[3]);
    lo = make_uint4(lw[0], lw[1], lw[2], lw[3]);
}

// ---------------------------------------------------------------------------
// setup1: per-cluster block. Computes A = L L^T + I, Cholesky Lc, invLc, w.
// NEW: emits invLc as bf16 hi/lo A-FRAGMENTS in per-lane order (row = t&31,
// c = 16*s + 8*(t>>5) + e) and -w in MFMA C-layout order, so main_kernel
// reads both with plain linear 16B loads -- no broadcast LDS reads remain.
// ---------------------------------------------------------------------------
__global__ __launch_bounds__(64) void setup1_kernel(
    const float* __restrict__ mu, const float* __restrict__ L,
    float* __restrict__ ws)
{
    __shared__ float sA[D][D + 1];
    __shared__ float sLc[D][D + 1];
    __shared__ float sI[D][D + 1];
    __shared__ float sWv[D];
    const int k = blockIdx.x;
    const int tid = threadIdx.x;
    const int i = tid & 31;
    const int row = tid & 31;
    const int hg = tid >> 5;

    for (int e = tid; e < D * D; e += 64) sI[e >> 5][e & 31] = L[k * D * D + e];
    __syncthreads();

    for (int e = tid; e < D * D; e += 64) {
        const int a = e >> 5, c = e & 31;
        float s = (a == c) ? 1.0f : 0.0f;
        #pragma unroll
        for (int b = 0; b < D; ++b) s = fmaf(sI[a][b], sI[c][b], s);
        sA[a][c] = s;
    }
    __syncthreads();

    float lrow[D];
    #pragma unroll
    for (int j = 0; j < D; ++j) {
        if (i == j) {
            float s = sA[j][j];
            #pragma unroll
            for (int b = 0; b < j; ++b) s = fmaf(-lrow[b], lrow[b], s);
            const float d = sqrtf(s);
            lrow[j] = d;
            #pragma unroll
            for (int b = 0; b < j; ++b) sLc[j][b] = lrow[b];
            sLc[j][j] = d;
        }
        __syncthreads();
        if (i > j) {
            float s = sA[i][j];
            #pragma unroll
            for (int b = 0; b < j; ++b) s = fmaf(-lrow[b], sLc[j][b], s);
            lrow[j] = s / sLc[j][j];
        }
    }
    __syncthreads();

    for (int e = tid; e < D * D; e += 64) {
        const int r = e >> 5, c = e & 31;
        ws[LCOFF + k * D * D + e] = (c <= r) ? sLc[r][c] : 0.0f;
    }

    {   // invLc column j (zeros above diagonal come out naturally)
        const int j = i;
        #pragma unroll
        for (int ii = 0; ii < D; ++ii) {
            float s = (ii == j) ? 1.0f : 0.0f;
            #pragma unroll
            for (int b = 0; b < ii; ++b) s = fmaf(-sLc[ii][b], sI[b][j], s);
            sI[ii][j] = s / sLc[ii][ii];
        }
    }
    __syncthreads();   // sI now full invLc (rows x cols)

    // w_k[i] = sum_b invLc[i][b] mu[b]
    {
        float s = 0.0f;
        #pragma unroll
        for (int b = 0; b < D; ++b) s = fmaf(sI[i][b], mu[k * D + b], s);
        if (tid < 32) sWv[i] = s;
    }

    // A-fragments: frag(k, s, hl) lane t holds row=t&31, c=16s+8*(t>>5)+e
    #pragma unroll
    for (int s = 0; s < 2; ++s) {
        float v[8];
        #pragma unroll
        for (int e = 0; e < 8; ++e) v[e] = sI[row][16 * s + 8 * hg + e];
        uint4 hi, lo;
        pack8(v, hi, lo);
        *(uint4*)((char*)ws + AFROFF * 4 + k * 4096 + ((s * 2 + 0) * 64 + tid) * 16) = hi;
        *(uint4*)((char*)ws + AFROFF * 4 + k * 4096 + ((s * 2 + 1) * 64 + tid) * 16) = lo;
    }
    __syncthreads();

    // -w in MFMA C-layout order: [k][half h][reg r] = -w[(r&3)+8*(r>>2)+4h]
    if (tid < 32) {
        const int h = tid >> 4, r = tid & 15;
        ws[WFROFF + k * 32 + h * 16 + r] = -sWv[(r & 3) + 8 * (r >> 2) + 4 * h];
    }
}

// ---------------------------------------------------------------------------
// setup2 (proven): pair constants c2, cmax; zeroes the finish ticket.
// ---------------------------------------------------------------------------
#define SLC(kk, r, c) sLc2[(kk) * 1024 + (r) * 32 + (c)]

__global__ __launch_bounds__(256) void setup2_kernel(
    const float* __restrict__ mu, const float* __restrict__ weights,
    float* __restrict__ ws)
{
    __shared__ float sLc2[K * D * D];   // 32 KB
    __shared__ float sMu[K * D];
    __shared__ float sWt[K];
    __shared__ float sLogw[K];
    __shared__ float sCp[NPAIR];
    __shared__ float sCmax;
    const int tid = threadIdx.x;

    {
        const float4* src = (const float4*)(ws + LCOFF);
        float4* dst = (float4*)sLc2;
        #pragma unroll
        for (int e = 0; e < 8; ++e) dst[tid + 256 * e] = src[tid + 256 * e];
        sMu[tid] = mu[tid];
        if (tid < K) sWt[tid] = weights[tid];
    }
    __syncthreads();

    if (tid == 0) {
        float m = -INFINITY;
        for (int t = 0; t < K; ++t) m = fmaxf(m, sWt[t]);
        float s = 0.0f;
        for (int t = 0; t < K; ++t) s += expf(sWt[t] - m);
        const float lse = m + logf(s);
        for (int t = 0; t < K; ++t) sLogw[t] = sWt[t] - lse;
        *(unsigned int*)(ws + TICKOFF) = 0u;
    }
    __syncthreads();

    if (tid < NPAIR) {
        int tt = tid, pi = 0;
        while (tt >= (K - pi)) { tt -= (K - pi); ++pi; }
        const int pj = pi + tt;
        const float LOG2PI = 1.8378770664093453f;
        float sumlogS = 0.0f, logdetsig = 0.0f;
        #pragma unroll
        for (int r = 0; r < D; ++r) {
            const float di = SLC(pi, r, r), dj = SLC(pj, r, r);
            sumlogS += logf(di + dj);
            logdetsig -= logf(1.0f / di + 1.0f / dj);
        }
        float v[D];
        float quad_acc = 0.0f;
        #pragma unroll
        for (int r = 0; r < D; ++r) {
            const float d0 = sMu[pi * D + r] - sMu[pj * D + r];
            float s = d0;
            #pragma unroll
            for (int b = 0; b < r; ++b)
                s = fmaf(-(SLC(pi, r, b) + SLC(pj, r, b)), v[b], s);
            v[r] = s / (SLC(pi, r, r) + SLC(pj, r, r));
            quad_acc = fmaf(d0, v[r], quad_acc);
        }
        const float quad = -0.5f * quad_acc;
        float c = quad - 0.5f * sumlogS - (float)D * LOG2PI - 0.5f * logdetsig
                  + sLogw[pi] + sLogw[pj];
        if (pi < pj) c += 0.6931471805599453f;
        sCp[tid] = c;
    }
    __syncthreads();
    if (tid == 0) {
        float m = -INFINITY;
        for (int t = 0; t < NPAIR; ++t) m = fmaxf(m, sCp[t]);
        sCmax = m;
        ws[CMAXOFF] = m;
    }
    __syncthreads();
    if (tid < NPAIR)
        ws[C2OFF + tid] = (sCp[tid] - sCmax) * 1.4426950408889634f;
}

// ---------------------------------------------------------------------------
// main v12 (MFMA): 256 thr = 4 independent waves, each owning 32 DISTINCT
// samples (sample = bid*128 + wv*32 + (lane&31)). Per k: y_k = invLc_k x - w
// via 6 x mfma_f32_32x32x16_bf16 (Ootomo hi/lo 3-term: AhBh + AlBh + AhBl),
// acc initialized to -w in C-layout order. A-frags pre-packed by setup1 ->
// plain linear global 16B loads (L2-hot 32KB). No LDS staging, no barriers
// until the final block reduce. Gram on the f32 accumulators: lane holds 16
// rows of its sample; per pair 16 FMA + one shfl_xor(32) half-combine on q.
// C/D layout is HW-verified (m74/m101); A/B k-mapping only needs A/B
// consistency (shared permutation cancels in the contraction); sample-column
// permutations are harmless (samples are summed).
// ---------------------------------------------------------------------------
__global__ __launch_bounds__(256) void main_kernel(
    const float* __restrict__ X, const float* __restrict__ cst,
    float* __restrict__ partials, float* __restrict__ out,
    unsigned int* __restrict__ ticket, int nsamp, int nblk)
{
    __shared__ float sRed[4];
    __shared__ int sIsLast;
    const int tid = threadIdx.x;
    const int wv = tid >> 6;
    const int lane = tid & 63;
    const int col = lane & 31;         // sample within wave group
    const int hg = lane >> 5;          // k-half / row-half selector

    const int n = blockIdx.x * 128 + wv * 32 + col;
    const int m = (n < nsamp) ? n : 0;

    // B-fragments from x (16 floats per lane: c = 8*hg+0..7 and 16+8*hg+0..7)
    FragU bh0, bl0, bh1, bl1;
    {
        const float4 a0 = *(const float4*)(X + m * D + 8 * hg);
        const float4 a1 = *(const float4*)(X + m * D + 8 * hg + 4);
        const float4 a2 = *(const float4*)(X + m * D + 16 + 8 * hg);
        const float4 a3 = *(const float4*)(X + m * D + 16 + 8 * hg + 4);
        float v0[8] = {a0.x, a0.y, a0.z, a0.w, a1.x, a1.y, a1.z, a1.w};
        float v1[8] = {a2.x, a2.y, a2.z, a2.w, a3.x, a3.y, a3.z, a3.w};
        pack8(v0, bh0.u4, bl0.u4);
        pack8(v1, bh1.u4, bl1.u4);
    }

    const char* afr = (const char*)cst;            // AFROFF == 0
    const float* wfr = cst + WFROFF;

    f32x16 yk[K];
    #pragma unroll
    for (int k = 0; k < K; ++k) {
        FragU ah0, al0, ah1, al1;
        ah0.u4 = *(const uint4*)(afr + k * 4096 + (0 * 64 + lane) * 16);
        al0.u4 = *(const uint4*)(afr + k * 4096 + (1 * 64 + lane) * 16);
        ah1.u4 = *(const uint4*)(afr + k * 4096 + (2 * 64 + lane) * 16);
        al1.u4 = *(const uint4*)(afr + k * 4096 + (3 * 64 + lane) * 16);

        f32x16 acc1;
        {
            const float4* wp = (const float4*)(wfr + k * 32 + hg * 16);
            const float4 w0 = wp[0], w1 = wp[1], w2 = wp[2], w3 = wp[3];
            acc1[0] = w0.x;  acc1[1] = w0.y;  acc1[2] = w0.z;  acc1[3] = w0.w;
            acc1[4] = w1.x;  acc1[5] = w1.y;  acc1[6] = w1.z;  acc1[7] = w1.w;
            acc1[8] = w2.x;  acc1[9] = w2.y;  acc1[10] = w2.z; acc1[11] = w2.w;
            acc1[12] = w3.x; acc1[13] = w3.y; acc1[14] = w3.z; acc1[15] = w3.w;
        }
        f32x16 acc2 = (f32x16)(0.0f);

        acc1 = __builtin_amdgcn_mfma_f32_32x32x16_bf16(ah0.s8, bh0.s8, acc1, 0, 0, 0);
        acc2 = __builtin_amdgcn_mfma_f32_32x32x16_bf16(al1.s8, bh1.s8, acc2, 0, 0, 0);
        acc1 = __builtin_amdgcn_mfma_f32_32x32x16_bf16(ah1.s8, bh1.s8, acc1, 0, 0, 0);
        acc2 = __builtin_amdgcn_mfma_f32_32x32x16_bf16(ah0.s8, bl0.s8, acc2, 0, 0, 0);
        acc1 = __builtin_amdgcn_mfma_f32_32x32x16_bf16(al0.s8, bh0.s8, acc1, 0, 0, 0);
        acc2 = __builtin_amdgcn_mfma_f32_32x32x16_bf16(ah1.s8, bl1.s8, acc2, 0, 0, 0);

        yk[k] = acc1 + acc2;
    }

    // Gram on accumulators: lane's 16 rows (half of 32; other half in lane^32)
    float G[NPAIR];
    #pragma unroll
    for (int pi = 0; pi < K; ++pi)
        #pragma unroll
        for (int pj = pi; pj < K; ++pj) {
            float g = 0.0f;
            #pragma unroll
            for (int r = 0; r < 16; ++r)
                g = fmaf(yk[pi][r], yk[pj][r], g);
            G[gidx(pi, pj)] = g;
        }

    float accs = 0.0f;
    const float NH = -0.72134752044448170f;   // -0.5*log2(e)
    #pragma unroll
    for (int pi = 0; pi < K; ++pi)
        #pragma unroll
        for (int pj = pi; pj < K; ++pj) {
            const float q = 2.0f * G[gidx(pi, pj)]
                          + G[gidx(pi, pi)] + G[gidx(pj, pj)];
            const float qf = q + __shfl_xor(q, 32, 64);   // combine row halves
            accs += exp2f(fmaf(NH, qf, cst[C2OFF + gidx(pi, pj)]));
        }
    accs = (n < nsamp) ? accs : 0.0f;

    // wave reduce (each sample duplicated in lane pair -> x0.5)
    #pragma unroll
    for (int s = 1; s < 64; s <<= 1) accs += __shfl_xor(accs, s, 64);
    if (lane == 0) sRed[wv] = 0.5f * accs;
    __syncthreads();

    if (tid == 0) {
        const float blocksum = sRed[0] + sRed[1] + sRed[2] + sRed[3];
        partials[blockIdx.x] = blocksum;
        __threadfence();                              // release partial
        const unsigned prev = atomicAdd(ticket, 1u);  // device scope (G12)
        sIsLast = (prev == (unsigned)(nblk - 1)) ? 1 : 0;
    }
    __syncthreads();

    if (sIsLast) {                                    // folded finish kernel
        __threadfence();                              // acquire partials
        float a2 = 0.0f;
        for (int e = tid; e < nblk; e += 256) a2 += partials[e];
        #pragma unroll
        for (int s = 1; s < 64; s <<= 1) a2 += __shfl_xor(a2, s, 64);
        if ((tid & 63) == 0) sRed[tid >> 6] = a2;
        __syncthreads();
        if (tid == 0)
            out[0] = cst[CMAXOFF]
                   + logf(sRed[0] + sRed[1] + sRed[2] + sRed[3]);
    }
}

extern "C" void kernel_launch(void* const* d_in, const int* in_sizes, int n_in,
                              void* d_out, int out_size, void* d_ws, size_t ws_size,
                              hipStream_t stream) {
    const float* X = (const float*)d_in[0];
    const float* mu = (const float*)d_in[1];
    const float* L = (const float*)d_in[2];
    const float* w = (const float*)d_in[3];
    float* wsf = (float*)d_ws;
    float* out = (float*)d_out;

    const int nsamp = in_sizes[0] / D;
    const int nblk = (nsamp + 127) / 128;   // 128 samples per 4-wave block

    setup1_kernel<<<K, 64, 0, stream>>>(mu, L, wsf);
    setup2_kernel<<<1, 256, 0, stream>>>(mu, w, wsf);
    main_kernel<<<nblk, 256, 0, stream>>>(X, wsf, wsf + PARTOFF, out,
                                          (unsigned int*)(wsf + TICKOFF),
                                          nsamp, nblk);
}